// Round 2
// baseline (969.698 us; speedup 1.0000x reference)
//
#include <hip/hip_runtime.h>
#include <math.h>

#define ACT_NONE 0
#define ACT_ELU  1
#define ACT_TANH 2

typedef unsigned short u16;
typedef unsigned int   u32;
typedef __attribute__((ext_vector_type(8))) short short8;  // 8 bf16 (4 VGPRs)
typedef __attribute__((ext_vector_type(4))) float f32x4;

__device__ __forceinline__ float eluf(float v) { return v > 0.f ? v : __expf(v) - 1.f; }
__device__ __forceinline__ float tanh_fast(float v) {
    float t = __expf(2.f * v);
    return 1.f - 2.f / (t + 1.f);
}
// fp32 -> bf16 round-nearest-even
__device__ __forceinline__ u16 bf16_rne(float x) {
    u32 u = __float_as_uint(x);
    u32 r = u + 0x7FFFu + ((u >> 16) & 1u);
    return (u16)(r >> 16);
}

// ---------------------------------------------------------------------------
// Elementwise fp32 -> bf16 hi/lo split, same layout. n multiple of 8.
// ---------------------------------------------------------------------------
__global__ __launch_bounds__(256) void splitX(
    const float* __restrict__ in, u16* __restrict__ hi, u16* __restrict__ lo, int n)
{
    int i = (blockIdx.x * 256 + threadIdx.x) * 8;
    if (i >= n) return;
    float4 v0 = reinterpret_cast<const float4*>(in + i)[0];
    float4 v1 = reinterpret_cast<const float4*>(in + i)[1];
    float f[8] = {v0.x, v0.y, v0.z, v0.w, v1.x, v1.y, v1.z, v1.w};
    alignas(16) u16 h[8], l[8];
#pragma unroll
    for (int e = 0; e < 8; ++e) {
        u16 hh = bf16_rne(f[e]);
        h[e] = hh;
        float hf = __uint_as_float((u32)hh << 16);
        l[e] = bf16_rne(f[e] - hf);
    }
    *reinterpret_cast<uint4*>(hi + i) = *reinterpret_cast<uint4*>(&h[0]);
    *reinterpret_cast<uint4*>(lo + i) = *reinterpret_cast<uint4*>(&l[0]);
}

// ---------------------------------------------------------------------------
// Transpose + fp32->bf16(hi/lo) convert.
// in: fp32 [K][N] row-major.  out: bf16 [Npad rows][ldo] (n-major, k-contiguous),
// zero-filled outside [K,N]. Grid: (ceil(Kpad/32), Npad/32), 256 threads.
// ---------------------------------------------------------------------------
__global__ __launch_bounds__(256) void convT(
    const float* __restrict__ in, int K, int N,
    u16* __restrict__ outHi, u16* __restrict__ outLo, int ldo)
{
    __shared__ float tile[32][33];
    const int t  = threadIdx.x;
    const int kt = blockIdx.x * 32;
    const int nt = blockIdx.y * 32;
    {
        int r = t >> 3, c = (t & 7) * 4;
        int gk = kt + r;
        float4 v = {0.f, 0.f, 0.f, 0.f};
        if (gk < K) {
            const float* p = in + (size_t)gk * N + nt + c;
            if (nt + c + 3 < N) {
                v = *reinterpret_cast<const float4*>(p);
            } else {
                if (nt + c + 0 < N) v.x = p[0];
                if (nt + c + 1 < N) v.y = p[1];
                if (nt + c + 2 < N) v.z = p[2];
                if (nt + c + 3 < N) v.w = p[3];
            }
        }
        tile[r][c] = v.x; tile[r][c + 1] = v.y; tile[r][c + 2] = v.z; tile[r][c + 3] = v.w;
    }
    __syncthreads();
    {
        int r = t >> 3, c = (t & 7) * 4;   // r = n within tile, c = k within tile
        ushort4 h, l;
        float f[4];
#pragma unroll
        for (int e = 0; e < 4; ++e) f[e] = tile[c + e][r];
        u16 hh[4], ll[4];
#pragma unroll
        for (int e = 0; e < 4; ++e) {
            hh[e] = bf16_rne(f[e]);
            float hf = __uint_as_float((u32)hh[e] << 16);
            ll[e] = bf16_rne(f[e] - hf);
        }
        h.x = hh[0]; h.y = hh[1]; h.z = hh[2]; h.w = hh[3];
        l.x = ll[0]; l.y = ll[1]; l.z = ll[2]; l.w = ll[3];
        size_t o = (size_t)(nt + r) * ldo + kt + c;
        *reinterpret_cast<ushort4*>(outHi + o) = h;
        *reinterpret_cast<ushort4*>(outLo + o) = l;
    }
}

// ---------------------------------------------------------------------------
// All-bf16 split-fp32 MFMA GEMM: C = act(A @ B + bias)   (or atomic += A@B)
//   A: pre-split bf16 hi/lo [M][lda] row-major (k-contiguous).
//   B: pre-split bf16 hi/lo [Npad][ldb] (n-major, k-contiguous).
//   3-term emulation: Ahi*Bhi + Ahi*Blo + Alo*Bhi  (~2^-17 rel err).
// 128x128 tile, BK=32, 256 threads = 4 waves (2x2 of 64x64), 16x16x32 MFMA.
// T14 async staging: next tile's global loads issue before this tile's MFMAs,
// LDS written after the trailing barrier (loads in flight across the compute).
// LDS rows padded to 40 u16 (80 B, 16B-aligned, low-conflict frag reads).
// ---------------------------------------------------------------------------
template <int ACT, bool ATOMIC>
__global__ __launch_bounds__(256) void mgemm2(
    const u16* __restrict__ Ahi, const u16* __restrict__ Alo, int lda,
    const u16* __restrict__ Bhi, const u16* __restrict__ Blo, int ldb,
    const float* __restrict__ bias,
    float* __restrict__ C, int ldc,
    int Ncols, int kChunk, int Ktot)
{
    __shared__ u16 As[2][128][40];   // [hi/lo][m][k]
    __shared__ u16 Bs[2][128][40];   // [hi/lo][n][k]

    const int tid  = threadIdx.x;
    const int m0   = blockIdx.y * 128;
    const int n0   = blockIdx.x * 128;
    const int kbeg = blockIdx.z * kChunk;
    const int kend = min(Ktot, kbeg + kChunk);

    const int w  = tid >> 6;
    const int wm = (w >> 1) * 64;
    const int wn = (w & 1) * 64;
    const int ln = tid & 63;
    const int fr = ln & 15;        // fragment row/col
    const int kh = ln >> 4;        // k-group (8 bf16 each)

    const int srow = tid >> 1;          // staging row 0..127
    const int skq  = (tid & 1) * 16;    // staging k-offset 0/16

    const u16* pAh = Ahi + (size_t)(m0 + srow) * lda + skq;
    const u16* pAl = Alo + (size_t)(m0 + srow) * lda + skq;
    const u16* pBh = Bhi + (size_t)(n0 + srow) * ldb + skq;
    const u16* pBl = Blo + (size_t)(n0 + srow) * ldb + skq;

    uint4 r0, r1, r2, r3, r4, r5, r6, r7;
#define LOADK(kk) do {                                                   \
        r0 = *reinterpret_cast<const uint4*>(pAh + (kk));                \
        r1 = *reinterpret_cast<const uint4*>(pAh + (kk) + 8);            \
        r2 = *reinterpret_cast<const uint4*>(pAl + (kk));                \
        r3 = *reinterpret_cast<const uint4*>(pAl + (kk) + 8);            \
        r4 = *reinterpret_cast<const uint4*>(pBh + (kk));                \
        r5 = *reinterpret_cast<const uint4*>(pBh + (kk) + 8);            \
        r6 = *reinterpret_cast<const uint4*>(pBl + (kk));                \
        r7 = *reinterpret_cast<const uint4*>(pBl + (kk) + 8);            \
    } while (0)

    f32x4 acc[4][4];
#pragma unroll
    for (int i = 0; i < 4; ++i)
#pragma unroll
        for (int j = 0; j < 4; ++j) {
            f32x4 z = {0.f, 0.f, 0.f, 0.f};
            acc[i][j] = z;
        }

    LOADK(kbeg);
    for (int k0 = kbeg; k0 < kend; k0 += 32) {
        // ---- write staged regs to LDS (vmcnt wait auto-inserted here) ----
        *reinterpret_cast<uint4*>(&As[0][srow][skq])     = r0;
        *reinterpret_cast<uint4*>(&As[0][srow][skq + 8]) = r1;
        *reinterpret_cast<uint4*>(&As[1][srow][skq])     = r2;
        *reinterpret_cast<uint4*>(&As[1][srow][skq + 8]) = r3;
        *reinterpret_cast<uint4*>(&Bs[0][srow][skq])     = r4;
        *reinterpret_cast<uint4*>(&Bs[0][srow][skq + 8]) = r5;
        *reinterpret_cast<uint4*>(&Bs[1][srow][skq])     = r6;
        *reinterpret_cast<uint4*>(&Bs[1][srow][skq + 8]) = r7;
        __syncthreads();

        // ---- prefetch next tile: loads fly during the MFMAs below ----
        if (k0 + 32 < kend) LOADK(k0 + 32);

        // ---- fragments + MFMA (A-row = lane&15, k = (lane>>4)*8 + e) ----
        short8 ah[4], al[4], bh[4], bl[4];
#pragma unroll
        for (int i = 0; i < 4; ++i) {
            ah[i] = *reinterpret_cast<const short8*>(&As[0][wm + i * 16 + fr][kh * 8]);
            al[i] = *reinterpret_cast<const short8*>(&As[1][wm + i * 16 + fr][kh * 8]);
        }
#pragma unroll
        for (int j = 0; j < 4; ++j) {
            bh[j] = *reinterpret_cast<const short8*>(&Bs[0][wn + j * 16 + fr][kh * 8]);
            bl[j] = *reinterpret_cast<const short8*>(&Bs[1][wn + j * 16 + fr][kh * 8]);
        }
#pragma unroll
        for (int i = 0; i < 4; ++i)
#pragma unroll
            for (int j = 0; j < 4; ++j) {
                acc[i][j] = __builtin_amdgcn_mfma_f32_16x16x32_bf16(ah[i], bh[j], acc[i][j], 0, 0, 0);
                acc[i][j] = __builtin_amdgcn_mfma_f32_16x16x32_bf16(ah[i], bl[j], acc[i][j], 0, 0, 0);
                acc[i][j] = __builtin_amdgcn_mfma_f32_16x16x32_bf16(al[i], bh[j], acc[i][j], 0, 0, 0);
            }
        __syncthreads();
    }
#undef LOADK

    // ---- epilogue: D mapping col = lane&15, row = (lane>>4)*4 + p  [m89] ----
#pragma unroll
    for (int j = 0; j < 4; ++j) {
        const int col = n0 + wn + j * 16 + fr;
        float bv = 0.f;
        if (!ATOMIC) bv = bias[col];
#pragma unroll
        for (int i = 0; i < 4; ++i) {
            const int rowb = m0 + wm + i * 16 + kh * 4;
#pragma unroll
            for (int p = 0; p < 4; ++p) {
                float v = acc[i][j][p];
                const int row = rowb + p;
                if (ATOMIC) {
                    if (col < Ncols) atomicAdd(&C[(size_t)row * ldc + col], v);
                } else {
                    v += bv;
                    if (ACT == ACT_TANH) v = tanh_fast(v);
                    else if (ACT == ACT_ELU) v = eluf(v);
                    C[(size_t)row * ldc + col] = v;
                }
            }
        }
    }
}

// ---------------------------------------------------------------------------
__global__ __launch_bounds__(256) void zero_f32(float* __restrict__ p, int n)
{
    int i = blockIdx.x * 256 + threadIdx.x;
    if (i < n) p[i] = 0.f;
}

__global__ __launch_bounds__(256) void bias_elu_inplace(
    float* __restrict__ p, const float* __restrict__ bias, int n, int N)
{
    int i = blockIdx.x * 256 + threadIdx.x;
    if (i < n) p[i] = eluf(p[i] + bias[i % N]);
}

// ---------------------------------------------------------------------------
// Row-per-block GEMM for small N/K: out[m,:] = act(A[m,:] @ W + bias)
// ---------------------------------------------------------------------------
template <int ACT>
__global__ __launch_bounds__(256) void rowgemm(
    const float* __restrict__ A, int strideA,
    const float* __restrict__ W, const float* __restrict__ bias,
    float* __restrict__ out, int strideOut, int padWidth,
    int N, int K)
{
    __shared__ float Arow[928];
    const int m = blockIdx.x;
    const int t = threadIdx.x;
    for (int k = t; k < K; k += 256) Arow[k] = A[(size_t)m * strideA + k];
    __syncthreads();
    for (int n = t; n < padWidth; n += 256) {
        float s = 0.f;
        if (n < N) {
            s = bias[n];
            for (int k = 0; k < K; ++k) s = fmaf(Arow[k], W[(size_t)k * N + n], s);
            if (ACT == ACT_ELU) s = eluf(s);
        }
        out[(size_t)m * strideOut + n] = s;
    }
}

// ---------------------------------------------------------------------------
// rowgemm variant writing bf16 hi/lo split output (ELU applied).
// Pads cols [N, padWidth) with zeros.
// ---------------------------------------------------------------------------
__global__ __launch_bounds__(256) void rowgemm_split(
    const float* __restrict__ A, int strideA,
    const float* __restrict__ W, const float* __restrict__ bias,
    u16* __restrict__ outHi, u16* __restrict__ outLo, int strideOut, int padWidth,
    int N, int K)
{
    __shared__ float Arow[928];
    const int m = blockIdx.x;
    const int t = threadIdx.x;
    for (int k = t; k < K; k += 256) Arow[k] = A[(size_t)m * strideA + k];
    __syncthreads();
    for (int n = t; n < padWidth; n += 256) {
        u16 hh = 0, ll = 0;
        if (n < N) {
            float s = bias[n];
            for (int k = 0; k < K; ++k) s = fmaf(Arow[k], W[(size_t)k * N + n], s);
            s = eluf(s);
            hh = bf16_rne(s);
            float hf = __uint_as_float((u32)hh << 16);
            ll = bf16_rne(s - hf);
        }
        outHi[(size_t)m * strideOut + n] = hh;
        outLo[(size_t)m * strideOut + n] = ll;
    }
}

// ---------------------------------------------------------------------------
// Latent: Bmat = W .* relu(j-i); eps = exp(logvar/2)*noise;
// z = forward substitution of z(I-B)=eps; Bz = z@Bmat.
// ---------------------------------------------------------------------------
__global__ __launch_bounds__(256) void latent_kernel(
    const float* __restrict__ logvar,
    const float* __restrict__ eps_noise,
    const float* __restrict__ Wlat,
    float* __restrict__ z_ws,
    float* __restrict__ out)
{
    __shared__ float Bm[256];
    const int t = threadIdx.x;
    {
        int i = t >> 4, j = t & 15;
        float v = (j > i) ? Wlat[t] * (float)(j - i) : 0.f;
        Bm[t] = v;
        if (blockIdx.x == 0) out[49152 + t] = v;        // Bmat
    }
    __syncthreads();

    const int b = blockIdx.x * 256 + t;
    float lv[16], z[16];
#pragma unroll
    for (int j = 0; j < 16; ++j) lv[j] = logvar[b * 16 + j];
#pragma unroll
    for (int j = 0; j < 16; ++j) {
        float s = __expf(0.5f * fminf(lv[j], 80.f)) * eps_noise[b * 16 + j];
        for (int i = 0; i < j; ++i) s = fmaf(z[i], Bm[i * 16 + j], s);
        z[j] = s;
    }
#pragma unroll
    for (int j = 0; j < 16; ++j) {
        float bz = 0.f;
#pragma unroll
        for (int i = 0; i < 16; ++i) bz = fmaf(z[i], Bm[i * 16 + j], bz);
        out[b * 16 + j]         = z[j];
        out[16384 + b * 16 + j] = lv[j];
        out[32768 + b * 16 + j] = bz;
        z_ws[b * 16 + j] = z[j];
    }
}

// ---------------------------------------------------------------------------
// Workspace layout (bytes) — total 269,467,648 (~257 MB):
//   h1     fp32 [1024][900]      @ 0
//   h2     fp32 [1024][300]      @ 3,686,400
//   lv     fp32 [1024][16]       @ 4,915,200
//   zf     fp32 [1024][16]       @ 4,980,736
//   g1     fp32 [1024][300]      @ 5,046,272
//   g2hi   bf16 [1024][320]      @ 6,275,072   (cols 300..319 = 0)
//   g2lo   bf16 [1024][320]      @ 6,930,432
//   xhi    bf16 [1024][27648]    @ 7,585,792
//   xlo    bf16 [1024][27648]    @ 64,208,896
//   w1t_hi bf16 [1024][27648]    @ 120,832,000 (rows 900..1023 = 0)
//   w1t_lo bf16 [1024][27648]    @ 177,455,104
//   w3t_hi bf16 [27648][320]     @ 234,078,208 (cols 300..319 = 0)
//   w3t_lo bf16 [27648][320]     @ 251,772,928
// Output (fp32 flat): z[16384] | logvar[16384] | Bz[16384] | Bmat[256] | xhat
// ---------------------------------------------------------------------------
extern "C" void kernel_launch(void* const* d_in, const int* in_sizes, int n_in,
                              void* d_out, int out_size, void* d_ws, size_t ws_size,
                              hipStream_t stream)
{
    const float* x       = (const float*)d_in[0];   // [1024, 27648]
    const float* eps_n   = (const float*)d_in[1];   // [1024, 16]
    const float* enc_w1  = (const float*)d_in[2];   // [27648, 900]
    const float* enc_b1  = (const float*)d_in[3];
    const float* enc_w2  = (const float*)d_in[4];   // [900, 300]
    const float* enc_b2  = (const float*)d_in[5];
    const float* lv_w    = (const float*)d_in[6];   // [300, 16]
    const float* lv_b    = (const float*)d_in[7];
    const float* Wlat    = (const float*)d_in[8];   // [16, 16]
    const float* dec_w1  = (const float*)d_in[9];   // [16, 300]
    const float* dec_b1  = (const float*)d_in[10];
    const float* dec_w2  = (const float*)d_in[11];  // [300, 300]
    const float* dec_b2  = (const float*)d_in[12];
    const float* dec_w3  = (const float*)d_in[13];  // [300, 27648]
    const float* dec_b3  = (const float*)d_in[14];

    char* ws = (char*)d_ws;
    float* h1     = (float*)(ws + 0);
    float* h2     = (float*)(ws + 3686400);
    float* lv     = (float*)(ws + 4915200);
    float* zf     = (float*)(ws + 4980736);
    float* g1     = (float*)(ws + 5046272);
    u16*   g2hi   = (u16*)(ws + 6275072);
    u16*   g2lo   = (u16*)(ws + 6930432);
    u16*   xhi    = (u16*)(ws + 7585792);
    u16*   xlo    = (u16*)(ws + 64208896);
    u16*   w1t_hi = (u16*)(ws + 120832000);
    u16*   w1t_lo = (u16*)(ws + 177455104);
    u16*   w3t_hi = (u16*)(ws + 234078208);
    u16*   w3t_lo = (u16*)(ws + 251772928);

    float* out = (float*)d_out;

    // 0) x -> bf16 hi/lo (28,311,552 elems, 8/thread)
    splitX<<<13824, 256, 0, stream>>>(x, xhi, xlo, 28311552);

    // 1) weight transpose + bf16 hi/lo split
    convT<<<dim3(864, 32), 256, 0, stream>>>(enc_w1, 27648, 900, w1t_hi, w1t_lo, 27648);
    convT<<<dim3(10, 864), 256, 0, stream>>>(dec_w3, 300, 27648, w3t_hi, w3t_lo, 320);

    // 2) zero split-K accumulator
    zero_f32<<<3600, 256, 0, stream>>>(h1, 921600);

    // 3) h1 += x @ enc_w1   (bf16x3 MFMA, split-K=16 -> 1024 blocks = 4/CU)
    mgemm2<ACT_NONE, true><<<dim3(8, 8, 16), 256, 0, stream>>>(
        xhi, xlo, 27648, w1t_hi, w1t_lo, 27648, nullptr,
        h1, 900, 900, 1728, 27648);

    // 4) h1 = elu(h1 + enc_b1)
    bias_elu_inplace<<<3600, 256, 0, stream>>>(h1, enc_b1, 921600, 900);

    // 5) h2 = elu(h1 @ enc_w2 + enc_b2)
    rowgemm<ACT_ELU><<<1024, 256, 0, stream>>>(
        h1, 900, enc_w2, enc_b2, h2, 300, 300, 300, 900);

    // 6) logvar = h2 @ lv_w + lv_b
    rowgemm<ACT_NONE><<<1024, 256, 0, stream>>>(
        h2, 300, lv_w, lv_b, lv, 16, 16, 16, 300);

    // 7) latent: z / logvar / Bz / Bmat outputs + fp32 z scratch
    latent_kernel<<<4, 256, 0, stream>>>(lv, eps_n, Wlat, zf, out);

    // 8) g1 = elu(z @ dec_w1 + dec_b1)
    rowgemm<ACT_ELU><<<1024, 256, 0, stream>>>(
        zf, 16, dec_w1, dec_b1, g1, 300, 300, 300, 16);

    // 9) g2 = elu(g1 @ dec_w2 + dec_b2) -> bf16 hi/lo, stride 320, pad zeroed
    rowgemm_split<<<1024, 256, 0, stream>>>(
        g1, 300, dec_w2, dec_b2, g2hi, g2lo, 320, 320, 300, 300);

    // 10) xhat = tanh(g2 @ dec_w3 + dec_b3)   (bf16x3 MFMA, K=320 incl. pad)
    mgemm2<ACT_TANH, false><<<dim3(216, 8, 1), 256, 0, stream>>>(
        g2hi, g2lo, 320, w3t_hi, w3t_lo, 320, dec_b3,
        out + 49408, 27648, 27648, 320, 320);
}

// Round 3
// 914.898 us; speedup vs baseline: 1.0599x; 1.0599x over previous
//
#include <hip/hip_runtime.h>
#include <math.h>

#define ACT_NONE 0
#define ACT_ELU  1
#define ACT_TANH 2

typedef unsigned short u16;
typedef unsigned int   u32;
typedef __attribute__((ext_vector_type(8))) short short8;  // 8 bf16 (4 VGPRs)
typedef __attribute__((ext_vector_type(4))) float f32x4;

__device__ __forceinline__ float eluf(float v) { return v > 0.f ? v : __expf(v) - 1.f; }
__device__ __forceinline__ float tanh_fast(float v) {
    float t = __expf(2.f * v);
    return 1.f - 2.f / (t + 1.f);
}
// fp32 -> bf16 round-nearest-even
__device__ __forceinline__ u16 bf16_rne(float x) {
    u32 u = __float_as_uint(x);
    u32 r = u + 0x7FFFu + ((u >> 16) & 1u);
    return (u16)(r >> 16);
}

// ---------------------------------------------------------------------------
// Transpose + fp32->bf16(hi/lo) convert.
// in: fp32 [K][N] row-major.  out: bf16 [Npad rows][ldo] (n-major, k-contiguous),
// zero-filled outside [K,N]. Grid: (ceil(Kpad/32), Npad/32), 256 threads.
// ---------------------------------------------------------------------------
__global__ __launch_bounds__(256) void convT(
    const float* __restrict__ in, int K, int N,
    u16* __restrict__ outHi, u16* __restrict__ outLo, int ldo)
{
    __shared__ float tile[32][33];
    const int t  = threadIdx.x;
    const int kt = blockIdx.x * 32;
    const int nt = blockIdx.y * 32;
    {
        int r = t >> 3, c = (t & 7) * 4;
        int gk = kt + r;
        float4 v = {0.f, 0.f, 0.f, 0.f};
        if (gk < K) {
            const float* p = in + (size_t)gk * N + nt + c;
            if (nt + c + 3 < N) {
                v = *reinterpret_cast<const float4*>(p);
            } else {
                if (nt + c + 0 < N) v.x = p[0];
                if (nt + c + 1 < N) v.y = p[1];
                if (nt + c + 2 < N) v.z = p[2];
                if (nt + c + 3 < N) v.w = p[3];
            }
        }
        tile[r][c] = v.x; tile[r][c + 1] = v.y; tile[r][c + 2] = v.z; tile[r][c + 3] = v.w;
    }
    __syncthreads();
    {
        int r = t >> 3, c = (t & 7) * 4;   // r = n within tile, c = k within tile
        ushort4 h, l;
        float f[4];
#pragma unroll
        for (int e = 0; e < 4; ++e) f[e] = tile[c + e][r];
        u16 hh[4], ll[4];
#pragma unroll
        for (int e = 0; e < 4; ++e) {
            hh[e] = bf16_rne(f[e]);
            float hf = __uint_as_float((u32)hh[e] << 16);
            ll[e] = bf16_rne(f[e] - hf);
        }
        h.x = hh[0]; h.y = hh[1]; h.z = hh[2]; h.w = hh[3];
        l.x = ll[0]; l.y = ll[1]; l.z = ll[2]; l.w = ll[3];
        size_t o = (size_t)(nt + r) * ldo + kt + c;
        *reinterpret_cast<ushort4*>(outHi + o) = h;
        *reinterpret_cast<ushort4*>(outLo + o) = l;
    }
}

// ---------------------------------------------------------------------------
// Split-fp32 MFMA GEMM, 3-term bf16 emulation (Ahi*Bhi + Ahi*Blo + Alo*Bhi).
//   AFP32=true : A fp32 [M][lda], split hi/lo in staging (VALU hidden by MFMA).
//   AFP32=false: A pre-split bf16 hi/lo [M][lda].
//   B: pre-split bf16 hi/lo [Npad][ldb] (n-major, k-contiguous).
//   PARTIAL=true: plain store to C + z*partStride (split-K partials, no atomics,
//   no bias/act, col guarded by Ncols).
// 128x128 tile, BK=32, 256 thr = 4 waves (2x2 of 64x64), 16x16x32 MFMA.
// 1-D grid, bijective XCD-chunked swizzle (T1): blocks sharing A/B panels land
// in the same XCD L2 chunk. gridDim.x must be a multiple of 8.
// Reg prefetch (T14): next tile's global loads issue before this tile's MFMAs.
// LDS rows padded to 40 u16 (80 B): ~2-way max on frag reads (free per m136).
// ---------------------------------------------------------------------------
template <int ACT, bool AFP32, bool PARTIAL>
__global__ __launch_bounds__(256) void mgemm3(
    const float* __restrict__ Af,
    const u16* __restrict__ Ahi, const u16* __restrict__ Alo, int lda,
    const u16* __restrict__ Bhi, const u16* __restrict__ Blo, int ldb,
    const float* __restrict__ bias,
    float* __restrict__ C, int ldc, int partStride,
    int Ncols, int kChunk, int Ktot, int nTiles, int mTiles)
{
    __shared__ u16 As[2][128][40];   // [hi/lo][m][k]
    __shared__ u16 Bs[2][128][40];   // [hi/lo][n][k]

    // ---- T1 bijective chunked swizzle (gridDim.x % 8 == 0) ----
    const int cpx = gridDim.x >> 3;
    const int lid = (blockIdx.x & 7) * cpx + (blockIdx.x >> 3);
    const int nT  = lid % nTiles;
    const int rem = lid / nTiles;
    const int mT  = rem % mTiles;
    const int z   = rem / mTiles;

    const int tid  = threadIdx.x;
    const int m0   = mT * 128;
    const int n0   = nT * 128;
    const int kbeg = z * kChunk;
    const int kend = min(Ktot, kbeg + kChunk);

    const int w  = tid >> 6;
    const int wm = (w >> 1) * 64;
    const int wn = (w & 1) * 64;
    const int ln = tid & 63;
    const int fr = ln & 15;        // fragment row/col
    const int kh = ln >> 4;        // k-group (8 bf16 each)

    const int srow = tid >> 1;          // staging row 0..127
    const int skq  = (tid & 1) * 16;    // staging k-offset 0/16

    const float* pAf = AFP32 ? (Af + (size_t)(m0 + srow) * lda + skq) : nullptr;
    const u16*   pAh = AFP32 ? nullptr : (Ahi + (size_t)(m0 + srow) * lda + skq);
    const u16*   pAl = AFP32 ? nullptr : (Alo + (size_t)(m0 + srow) * lda + skq);
    const u16*   pBh = Bhi + (size_t)(n0 + srow) * ldb + skq;
    const u16*   pBl = Blo + (size_t)(n0 + srow) * ldb + skq;

    float4 fa0, fa1, fa2, fa3;                  // AFP32 prefetch regs
    uint4  r0, r1, r2, r3;                      // !AFP32 prefetch regs
    uint4  r4, r5, r6, r7;                      // B prefetch regs

    auto LOADK = [&](int kk) {
        if constexpr (AFP32) {
            fa0 = reinterpret_cast<const float4*>(pAf + kk)[0];
            fa1 = reinterpret_cast<const float4*>(pAf + kk)[1];
            fa2 = reinterpret_cast<const float4*>(pAf + kk)[2];
            fa3 = reinterpret_cast<const float4*>(pAf + kk)[3];
        } else {
            r0 = *reinterpret_cast<const uint4*>(pAh + kk);
            r1 = *reinterpret_cast<const uint4*>(pAh + kk + 8);
            r2 = *reinterpret_cast<const uint4*>(pAl + kk);
            r3 = *reinterpret_cast<const uint4*>(pAl + kk + 8);
        }
        r4 = *reinterpret_cast<const uint4*>(pBh + kk);
        r5 = *reinterpret_cast<const uint4*>(pBh + kk + 8);
        r6 = *reinterpret_cast<const uint4*>(pBl + kk);
        r7 = *reinterpret_cast<const uint4*>(pBl + kk + 8);
    };

    f32x4 acc[4][4];
#pragma unroll
    for (int i = 0; i < 4; ++i)
#pragma unroll
        for (int j = 0; j < 4; ++j) {
            f32x4 zz = {0.f, 0.f, 0.f, 0.f};
            acc[i][j] = zz;
        }

    LOADK(kbeg);
    for (int k0 = kbeg; k0 < kend; k0 += 32) {
        // ---- write staged regs to LDS (vmcnt wait auto-inserted) ----
        if constexpr (AFP32) {
            alignas(16) float vv[16];
            *reinterpret_cast<float4*>(&vv[0])  = fa0;
            *reinterpret_cast<float4*>(&vv[4])  = fa1;
            *reinterpret_cast<float4*>(&vv[8])  = fa2;
            *reinterpret_cast<float4*>(&vv[12]) = fa3;
            alignas(16) u16 hh[16], ll[16];
#pragma unroll
            for (int e = 0; e < 16; ++e) {
                u16 h = bf16_rne(vv[e]);
                hh[e] = h;
                float hf = __uint_as_float((u32)h << 16);
                ll[e] = bf16_rne(vv[e] - hf);
            }
            *reinterpret_cast<uint4*>(&As[0][srow][skq])     = *reinterpret_cast<uint4*>(&hh[0]);
            *reinterpret_cast<uint4*>(&As[0][srow][skq + 8]) = *reinterpret_cast<uint4*>(&hh[8]);
            *reinterpret_cast<uint4*>(&As[1][srow][skq])     = *reinterpret_cast<uint4*>(&ll[0]);
            *reinterpret_cast<uint4*>(&As[1][srow][skq + 8]) = *reinterpret_cast<uint4*>(&ll[8]);
        } else {
            *reinterpret_cast<uint4*>(&As[0][srow][skq])     = r0;
            *reinterpret_cast<uint4*>(&As[0][srow][skq + 8]) = r1;
            *reinterpret_cast<uint4*>(&As[1][srow][skq])     = r2;
            *reinterpret_cast<uint4*>(&As[1][srow][skq + 8]) = r3;
        }
        *reinterpret_cast<uint4*>(&Bs[0][srow][skq])     = r4;
        *reinterpret_cast<uint4*>(&Bs[0][srow][skq + 8]) = r5;
        *reinterpret_cast<uint4*>(&Bs[1][srow][skq])     = r6;
        *reinterpret_cast<uint4*>(&Bs[1][srow][skq + 8]) = r7;
        __syncthreads();

        // ---- prefetch next tile: loads fly during the MFMAs below ----
        if (k0 + 32 < kend) LOADK(k0 + 32);

        // ---- fragments + MFMA (A-row = lane&15, k = (lane>>4)*8 + e) ----
        short8 ah[4], al[4], bh[4], bl[4];
#pragma unroll
        for (int i = 0; i < 4; ++i) {
            ah[i] = *reinterpret_cast<const short8*>(&As[0][wm + i * 16 + fr][kh * 8]);
            al[i] = *reinterpret_cast<const short8*>(&As[1][wm + i * 16 + fr][kh * 8]);
        }
#pragma unroll
        for (int j = 0; j < 4; ++j) {
            bh[j] = *reinterpret_cast<const short8*>(&Bs[0][wn + j * 16 + fr][kh * 8]);
            bl[j] = *reinterpret_cast<const short8*>(&Bs[1][wn + j * 16 + fr][kh * 8]);
        }
#pragma unroll
        for (int i = 0; i < 4; ++i)
#pragma unroll
            for (int j = 0; j < 4; ++j) {
                acc[i][j] = __builtin_amdgcn_mfma_f32_16x16x32_bf16(ah[i], bh[j], acc[i][j], 0, 0, 0);
                acc[i][j] = __builtin_amdgcn_mfma_f32_16x16x32_bf16(ah[i], bl[j], acc[i][j], 0, 0, 0);
                acc[i][j] = __builtin_amdgcn_mfma_f32_16x16x32_bf16(al[i], bh[j], acc[i][j], 0, 0, 0);
            }
        __syncthreads();
    }

    // ---- epilogue: D mapping col = lane&15, row = (lane>>4)*4 + p  [m89] ----
    float* Cz = PARTIAL ? (C + (size_t)z * partStride) : C;
#pragma unroll
    for (int j = 0; j < 4; ++j) {
        const int col = n0 + wn + j * 16 + fr;
        float bv = 0.f;
        if (!PARTIAL) bv = bias[col];
#pragma unroll
        for (int i = 0; i < 4; ++i) {
            const int rowb = m0 + wm + i * 16 + kh * 4;
#pragma unroll
            for (int p = 0; p < 4; ++p) {
                float v = acc[i][j][p];
                const int row = rowb + p;
                if (PARTIAL) {
                    if (col < Ncols) Cz[(size_t)row * ldc + col] = v;
                } else {
                    v += bv;
                    if (ACT == ACT_TANH) v = tanh_fast(v);
                    else if (ACT == ACT_ELU) v = eluf(v);
                    Cz[(size_t)row * ldc + col] = v;
                }
            }
        }
    }
}

// ---------------------------------------------------------------------------
// h1 = elu(sum_z part[z] + bias). n mult of 4, N mult of 4.
// ---------------------------------------------------------------------------
__global__ __launch_bounds__(256) void reduce_bias_elu(
    const float* __restrict__ part, const float* __restrict__ bias,
    float* __restrict__ out, int n, int N, int nz, int partStride)
{
    int i = (blockIdx.x * 256 + threadIdx.x) * 4;
    if (i >= n) return;
    float4 s = *reinterpret_cast<const float4*>(part + i);
    for (int z = 1; z < nz; ++z) {
        float4 p = *reinterpret_cast<const float4*>(part + (size_t)z * partStride + i);
        s.x += p.x; s.y += p.y; s.z += p.z; s.w += p.w;
    }
    int c = i % N;                                   // i%4==0, N%4==0 -> aligned
    float4 b = *reinterpret_cast<const float4*>(bias + c);
    s.x = eluf(s.x + b.x); s.y = eluf(s.y + b.y);
    s.z = eluf(s.z + b.z); s.w = eluf(s.w + b.w);
    *reinterpret_cast<float4*>(out + i) = s;
}

// ---------------------------------------------------------------------------
// Row-per-block GEMM for small N/K: out[m,:] = act(A[m,:] @ W + bias)
// ---------------------------------------------------------------------------
template <int ACT>
__global__ __launch_bounds__(256) void rowgemm(
    const float* __restrict__ A, int strideA,
    const float* __restrict__ W, const float* __restrict__ bias,
    float* __restrict__ out, int strideOut, int padWidth,
    int N, int K)
{
    __shared__ float Arow[928];
    const int m = blockIdx.x;
    const int t = threadIdx.x;
    for (int k = t; k < K; k += 256) Arow[k] = A[(size_t)m * strideA + k];
    __syncthreads();
    for (int n = t; n < padWidth; n += 256) {
        float s = 0.f;
        if (n < N) {
            s = bias[n];
            for (int k = 0; k < K; ++k) s = fmaf(Arow[k], W[(size_t)k * N + n], s);
            if (ACT == ACT_ELU) s = eluf(s);
        }
        out[(size_t)m * strideOut + n] = s;
    }
}

// ---------------------------------------------------------------------------
// rowgemm variant writing bf16 hi/lo split output (ELU applied).
// Pads cols [N, padWidth) with zeros.
// ---------------------------------------------------------------------------
__global__ __launch_bounds__(256) void rowgemm_split(
    const float* __restrict__ A, int strideA,
    const float* __restrict__ W, const float* __restrict__ bias,
    u16* __restrict__ outHi, u16* __restrict__ outLo, int strideOut, int padWidth,
    int N, int K)
{
    __shared__ float Arow[928];
    const int m = blockIdx.x;
    const int t = threadIdx.x;
    for (int k = t; k < K; k += 256) Arow[k] = A[(size_t)m * strideA + k];
    __syncthreads();
    for (int n = t; n < padWidth; n += 256) {
        u16 hh = 0, ll = 0;
        if (n < N) {
            float s = bias[n];
            for (int k = 0; k < K; ++k) s = fmaf(Arow[k], W[(size_t)k * N + n], s);
            s = eluf(s);
            hh = bf16_rne(s);
            float hf = __uint_as_float((u32)hh << 16);
            ll = bf16_rne(s - hf);
        }
        outHi[(size_t)m * strideOut + n] = hh;
        outLo[(size_t)m * strideOut + n] = ll;
    }
}

// ---------------------------------------------------------------------------
// Latent: Bmat = W .* relu(j-i); eps = exp(logvar/2)*noise;
// z = forward substitution of z(I-B)=eps; Bz = z@Bmat.
// ---------------------------------------------------------------------------
__global__ __launch_bounds__(256) void latent_kernel(
    const float* __restrict__ logvar,
    const float* __restrict__ eps_noise,
    const float* __restrict__ Wlat,
    float* __restrict__ z_ws,
    float* __restrict__ out)
{
    __shared__ float Bm[256];
    const int t = threadIdx.x;
    {
        int i = t >> 4, j = t & 15;
        float v = (j > i) ? Wlat[t] * (float)(j - i) : 0.f;
        Bm[t] = v;
        if (blockIdx.x == 0) out[49152 + t] = v;        // Bmat
    }
    __syncthreads();

    const int b = blockIdx.x * 256 + t;
    float lv[16], z[16];
#pragma unroll
    for (int j = 0; j < 16; ++j) lv[j] = logvar[b * 16 + j];
#pragma unroll
    for (int j = 0; j < 16; ++j) {
        float s = __expf(0.5f * fminf(lv[j], 80.f)) * eps_noise[b * 16 + j];
        for (int i = 0; i < j; ++i) s = fmaf(z[i], Bm[i * 16 + j], s);
        z[j] = s;
    }
#pragma unroll
    for (int j = 0; j < 16; ++j) {
        float bz = 0.f;
#pragma unroll
        for (int i = 0; i < 16; ++i) bz = fmaf(z[i], Bm[i * 16 + j], bz);
        out[b * 16 + j]         = z[j];
        out[16384 + b * 16 + j] = lv[j];
        out[32768 + b * 16 + j] = bz;
        z_ws[b * 16 + j] = z[j];
    }
}

// ---------------------------------------------------------------------------
// Workspace layout (bytes) — total 215,203,840 (~205 MB):
//   part   fp32 [16][1024][900]  @ 0             (58,982,400)
//   h1     fp32 [1024][900]      @ 58,982,400
//   h2     fp32 [1024][300]      @ 62,668,800
//   lv     fp32 [1024][16]       @ 63,897,600
//   zf     fp32 [1024][16]       @ 63,963,136
//   g1     fp32 [1024][300]      @ 64,028,672
//   g2hi   bf16 [1024][320]      @ 65,257,472   (cols 300..319 = 0)
//   g2lo   bf16 [1024][320]      @ 65,912,832
//   w1t_hi bf16 [1024][27648]    @ 66,568,192   (rows 900..1023 = 0)
//   w1t_lo bf16 [1024][27648]    @ 123,191,296
//   w3t_hi bf16 [27648][320]     @ 179,814,400  (cols 300..319 = 0)
//   w3t_lo bf16 [27648][320]     @ 197,509,120
// Output (fp32 flat): z[16384] | logvar[16384] | Bz[16384] | Bmat[256] | xhat
// ---------------------------------------------------------------------------
extern "C" void kernel_launch(void* const* d_in, const int* in_sizes, int n_in,
                              void* d_out, int out_size, void* d_ws, size_t ws_size,
                              hipStream_t stream)
{
    const float* x       = (const float*)d_in[0];   // [1024, 27648]
    const float* eps_n   = (const float*)d_in[1];   // [1024, 16]
    const float* enc_w1  = (const float*)d_in[2];   // [27648, 900]
    const float* enc_b1  = (const float*)d_in[3];
    const float* enc_w2  = (const float*)d_in[4];   // [900, 300]
    const float* enc_b2  = (const float*)d_in[5];
    const float* lv_w    = (const float*)d_in[6];   // [300, 16]
    const float* lv_b    = (const float*)d_in[7];
    const float* Wlat    = (const float*)d_in[8];   // [16, 16]
    const float* dec_w1  = (const float*)d_in[9];   // [16, 300]
    const float* dec_b1  = (const float*)d_in[10];
    const float* dec_w2  = (const float*)d_in[11];  // [300, 300]
    const float* dec_b2  = (const float*)d_in[12];
    const float* dec_w3  = (const float*)d_in[13];  // [300, 27648]
    const float* dec_b3  = (const float*)d_in[14];

    char* ws = (char*)d_ws;
    float* part   = (float*)(ws + 0);
    float* h1     = (float*)(ws + 58982400);
    float* h2     = (float*)(ws + 62668800);
    float* lv     = (float*)(ws + 63897600);
    float* zf     = (float*)(ws + 63963136);
    float* g1     = (float*)(ws + 64028672);
    u16*   g2hi   = (u16*)(ws + 65257472);
    u16*   g2lo   = (u16*)(ws + 65912832);
    u16*   w1t_hi = (u16*)(ws + 66568192);
    u16*   w1t_lo = (u16*)(ws + 123191296);
    u16*   w3t_hi = (u16*)(ws + 179814400);
    u16*   w3t_lo = (u16*)(ws + 197509120);

    float* out = (float*)d_out;

    // 0) weight transpose + bf16 hi/lo split
    convT<<<dim3(864, 32), 256, 0, stream>>>(enc_w1, 27648, 900, w1t_hi, w1t_lo, 27648);
    convT<<<dim3(10, 864), 256, 0, stream>>>(dec_w3, 300, 27648, w3t_hi, w3t_lo, 320);

    // 1) part[z] = x @ enc_w1 (k-chunk z)  — fp32 A split in-kernel,
    //    split-K=16 partials (no atomics, no pre-zero), XCD-swizzled grid.
    //    grid = 8n x 8m x 16z = 1024 blocks (4/CU by LDS)
    mgemm3<ACT_NONE, true, true><<<1024, 256, 0, stream>>>(
        x, nullptr, nullptr, 27648,
        w1t_hi, w1t_lo, 27648, nullptr,
        part, 900, 921600, 900, 1728, 27648, 8, 8);

    // 2) h1 = elu(sum_z part[z] + enc_b1)
    reduce_bias_elu<<<900, 256, 0, stream>>>(part, enc_b1, h1, 921600, 900, 16, 921600);

    // 3) h2 = elu(h1 @ enc_w2 + enc_b2)
    rowgemm<ACT_ELU><<<1024, 256, 0, stream>>>(
        h1, 900, enc_w2, enc_b2, h2, 300, 300, 300, 900);

    // 4) logvar = h2 @ lv_w + lv_b
    rowgemm<ACT_NONE><<<1024, 256, 0, stream>>>(
        h2, 300, lv_w, lv_b, lv, 16, 16, 16, 300);

    // 5) latent: z / logvar / Bz / Bmat outputs + fp32 z scratch
    latent_kernel<<<4, 256, 0, stream>>>(lv, eps_n, Wlat, zf, out);

    // 6) g1 = elu(z @ dec_w1 + dec_b1)
    rowgemm<ACT_ELU><<<1024, 256, 0, stream>>>(
        zf, 16, dec_w1, dec_b1, g1, 300, 300, 300, 16);

    // 7) g2 = elu(g1 @ dec_w2 + dec_b2) -> bf16 hi/lo, stride 320, pad zeroed
    rowgemm_split<<<1024, 256, 0, stream>>>(
        g1, 300, dec_w2, dec_b2, g2hi, g2lo, 320, 320, 300, 300);

    // 8) xhat = tanh(g2 @ dec_w3 + dec_b3)  — bf16-pair A, K=320 incl. pad,
    //    grid = 216n x 8m = 1728 blocks, XCD-swizzled (one m-strip per chunk)
    mgemm3<ACT_TANH, false, false><<<1728, 256, 0, stream>>>(
        nullptr, g2hi, g2lo, 320,
        w3t_hi, w3t_lo, 320, dec_b3,
        out + 49408, 27648, 0, 27648, 320, 320, 216, 8);
}